// Round 9
// baseline (61.325 us; speedup 1.0000x reference)
//
#include <hip/hip_runtime.h>
#include <math.h>

#define N_ROWS 131072
#define U2_OFF 4096   // floats: swT = ws[0..4095] ([256][16]), U2 = ws[4096..4351] (16x16)
#define ZXST 20       // z-exchange lane stride (floats): (5r)&7 distinct per phase

// ---------------- stage-1 builder: 8-qubit state, 4 amps/lane ----------------
__device__ __forceinline__ void ry8(float v[4], int lane, int bp, float c, float s) {
  if (bp == 0) {
    float n0 = fmaf(s, v[1], c * v[0]);
    float n1 = fmaf(-s, v[0], c * v[1]);
    float n2 = fmaf(s, v[3], c * v[2]);
    float n3 = fmaf(-s, v[2], c * v[3]);
    v[0] = n0; v[1] = n1; v[2] = n2; v[3] = n3;
  } else if (bp == 1) {
    float n0 = fmaf(s, v[2], c * v[0]);
    float n2 = fmaf(-s, v[0], c * v[2]);
    float n1 = fmaf(s, v[3], c * v[1]);
    float n3 = fmaf(-s, v[1], c * v[3]);
    v[0] = n0; v[1] = n1; v[2] = n2; v[3] = n3;
  } else {
    int lm = 1 << (bp - 2);
    float sgn = ((lane >> (bp - 2)) & 1) ? -s : s;
#pragma unroll
    for (int k = 0; k < 4; ++k) {
      float o = __shfl_xor(v[k], lm);
      v[k] = fmaf(sgn, o, c * v[k]);
    }
  }
}

__device__ __forceinline__ void cnot8(float v[4], int lane, int cb, int tb) {
  if (cb >= 2 && tb >= 2) {
    int lm = 1 << (tb - 2);
    bool hc = (lane >> (cb - 2)) & 1;
#pragma unroll
    for (int k = 0; k < 4; ++k) {
      float o = __shfl_xor(v[k], lm);
      v[k] = hc ? o : v[k];
    }
  } else if (cb >= 2) {
    bool hc = (lane >> (cb - 2)) & 1;
    if (tb == 0) {
      float n0 = hc ? v[1] : v[0], n1 = hc ? v[0] : v[1];
      float n2 = hc ? v[3] : v[2], n3 = hc ? v[2] : v[3];
      v[0] = n0; v[1] = n1; v[2] = n2; v[3] = n3;
    } else {
      float n0 = hc ? v[2] : v[0], n2 = hc ? v[0] : v[2];
      float n1 = hc ? v[3] : v[1], n3 = hc ? v[1] : v[3];
      v[0] = n0; v[1] = n1; v[2] = n2; v[3] = n3;
    }
  } else if (tb >= 2) {
    int lm = 1 << (tb - 2);
#pragma unroll
    for (int k = 0; k < 4; ++k) {
      float o = __shfl_xor(v[k], lm);
      if ((k >> cb) & 1) v[k] = o;
    }
  } else {
    if (cb == 0) { float t = v[1]; v[1] = v[3]; v[3] = t; }
    else         { float t = v[2]; v[2] = v[3]; v[3] = t; }
  }
}

// ---------------- stage-2 builder: full 16-dim state in registers ----------------
template <int BP>
__device__ __forceinline__ void ry16t(float* w, float c, float s) {
#pragma unroll
  for (int i = 0; i < 16; ++i) {
    if (((i >> BP) & 1) == 0) {
      const int j = i | (1 << BP);
      float a = w[i], b = w[j];
      w[i] = fmaf(s, b, c * a);
      w[j] = fmaf(-s, a, c * b);
    }
  }
}
__device__ __forceinline__ void ry16(float* w, int bp, float c, float s) {
  switch (bp) {
    case 0: ry16t<0>(w, c, s); break;
    case 1: ry16t<1>(w, c, s); break;
    case 2: ry16t<2>(w, c, s); break;
    default: ry16t<3>(w, c, s); break;
  }
}
template <int CB, int TB>
__device__ __forceinline__ void cnot16t(float* w) {
#pragma unroll
  for (int i = 0; i < 16; ++i) {
    if (((i >> CB) & 1) == 1 && ((i >> TB) & 1) == 0) {
      const int j = i | (1 << TB);
      float t = w[i]; w[i] = w[j]; w[j] = t;
    }
  }
}
__device__ __forceinline__ void cnot16(float* w, int cb, int tb) {
#define CC(a, b) if (cb == a && tb == b) { cnot16t<a, b>(w); return; }
  CC(0,1) CC(0,2) CC(0,3) CC(1,0) CC(1,2) CC(1,3)
  CC(2,0) CC(2,1) CC(2,3) CC(3,0) CC(3,1) CC(3,2)
#undef CC
}

__global__ void build_states_kernel(const float* __restrict__ thc,
                                    const float* __restrict__ th2,
                                    float* __restrict__ ws) {
  const int blk = blockIdx.x;
  const int lane = threadIdx.x;  // 64 threads
  if (blk < 16) {
    const float* th = thc + blk * 72;
    float v[4] = {0.f, 0.f, 0.f, 0.f};
    if (lane == 0) v[0] = 1.f;
    int p = 0;
    for (int m = 0; m < 8; ++m) {
#pragma unroll
      for (int q = 0; q < 8; ++q) {
        float a = 0.5f * th[p + q];
        ry8(v, lane, 7 - q, cosf(a), sinf(a));
      }
      p += 8;
#pragma unroll
      for (int q = 0; q < 8; ++q) {
        int tgt = (m % 2 == 0) ? ((q + 1) & 7) : ((q + 7) & 7);
        cnot8(v, lane, 7 - q, 7 - tgt);
      }
    }
#pragma unroll
    for (int q = 0; q < 8; ++q) {
      float a = 0.5f * th[p + q];
      ry8(v, lane, 7 - q, cosf(a), sinf(a));
    }
    // TRANSPOSED store: swT[k][c], k = 4*lane + kk, c = blk
#pragma unroll
    for (int kk = 0; kk < 4; ++kk) ws[(4 * lane + kk) * 16 + blk] = v[kk];
  } else {
    float w[16];
#pragma unroll
    for (int j = 0; j < 16; ++j) w[j] = (j == lane) ? 1.f : 0.f;
    int p = 0;
    for (int m = 0; m < 8; ++m) {
#pragma unroll
      for (int q = 0; q < 4; ++q) {
        float a = 0.5f * th2[p + q];
        ry16(w, 3 - q, cosf(a), sinf(a));
      }
      p += 4;
#pragma unroll
      for (int q = 0; q < 4; ++q) {
        int tgt = (m % 2 == 0) ? ((q + 1) & 3) : ((q + 3) & 3);
        cnot16(w, 3 - q, 3 - tgt);
      }
    }
#pragma unroll
    for (int q = 0; q < 4; ++q) {
      float a = 0.5f * th2[p + q];
      ry16(w, 3 - q, cosf(a), sinf(a));
    }
    if (lane < 16) {
      float* u2 = ws + U2_OFF;
#pragma unroll
      for (int j = 0; j < 16; ++j) u2[lane * 16 + j] = w[j];
    }
  }
}

__device__ __forceinline__ float silu_g(float z) {
  float v = z / (1.f + __expf(-z));
  return isfinite(v) ? v : 0.f;
}

// async global -> LDS, 16 B per lane (wave-uniform LDS base + lane*16)
__device__ __forceinline__ void stage16(const float* g, float* l) {
  __builtin_amdgcn_global_load_lds(
      (const __attribute__((address_space(1))) void*)g,
      (__attribute__((address_space(3))) void*)l, 16, 0, 0);
}

// 16 FMAs: per-lane x element * wave-uniform swT row (s_load -> SGPR operand)
#define FMA16(xe, sp)                                                          \
  {                                                                            \
    const float xe_ = (xe);                                                    \
    const float* __restrict__ s_ = (sp);                                       \
    _Pragma("unroll") for (int c = 0; c < 16; ++c)                             \
        z[c] = fmaf(xe_, s_[c], z[c]);                                         \
  }

// ---------------- main kernel ----------------
// Block = 256 thr = 4 waves, 64 rows. x staged via global_load_lds (width 16)
// into a 4-slot ring of [64 rows x 32 k] chunks; 3 chunks in flight per wave
// with COUNTED s_waitcnt vmcnt(4/2/0) (never a mid-loop full drain) + raw
// s_barrier -- one barrier per chunk. Quad-rotation swizzle (source-side,
// G21) makes the 128B-stride ds_read_b128 conflict-free: logical quad q of
// row r lives at physical p=(q+(r&7))&7. Wave w owns k-quarter [w*8,w*8+8)
// -> sw stays wave-uniform -> s_load -> free SGPR operands. z partials
// combined via LDS (aliased over the staging buffers after the loop); wave 0
// runs the per-lane epilogue (normalizations folded out: U2 orthogonal,
// final P-norm scale-invariant).
__global__ __launch_bounds__(256, 4) void hadamard_main_kernel(
    const float* __restrict__ x, const float* __restrict__ ws,
    float* __restrict__ out) {
  __shared__ __align__(16) float xs[4][64][32];  // 32 KB ring (4 x 8 KB)

  const int t = threadIdx.x;
  const int lane = t & 63;
  const int w = __builtin_amdgcn_readfirstlane(t >> 6);  // wave id = k-quarter
  const int rb = blockIdx.x * 64;

  const float* __restrict__ swT = ws;  // [256][16]

  // staging geometry: wave w stages rows 16w..16w+15 (2 insts of 8 rows)
  const int srow = (lane >> 3);                 // 0..7 within 8-row group
  const int qlog = ((lane & 7) - srow) & 7;     // pre-swizzled logical quad
  const float* g0 = x + (size_t)(rb + 16 * w + srow) * 256 + qlog * 4;
  const float* g1 = g0 + 8 * 256;

#define ISSUE(ck)                                                              \
  {                                                                            \
    const int sl_ = (ck) & 3;                                                  \
    stage16(g0 + (ck) * 32, &xs[sl_][16 * w][0]);                              \
    stage16(g1 + (ck) * 32, &xs[sl_][16 * w + 8][0]);                          \
  }

  float z[16];
#pragma unroll
  for (int c = 0; c < 16; ++c) z[c] = 0.f;

  // prologue: 3 chunks in flight
  ISSUE(0) ISSUE(1) ISSUE(2)

  // read-side swizzle for this lane: physical quads for logical 2w, 2w+1
  const int p0 = ((2 * w) + (lane & 7)) & 7;
  const int p1 = ((2 * w + 1) + (lane & 7)) & 7;

#pragma unroll 1
  for (int ck = 0; ck < 8; ++ck) {
    if (ck < 6)      asm volatile("s_waitcnt vmcnt(4)" ::: "memory");
    else if (ck == 6) asm volatile("s_waitcnt vmcnt(2)" ::: "memory");
    else             asm volatile("s_waitcnt vmcnt(0)" ::: "memory");
    __builtin_amdgcn_s_barrier();   // all waves' chunk-ck loads now visible

    const int sl = ck & 3;
    const float4 xq0 = *(const float4*)&xs[sl][lane][p0 * 4];
    const float4 xq1 = *(const float4*)&xs[sl][lane][p1 * 4];

    const float* __restrict__ sb = swT + (size_t)(ck * 32 + w * 8) * 16;
    FMA16(xq0.x, sb + 0)  FMA16(xq0.y, sb + 16) FMA16(xq0.z, sb + 32) FMA16(xq0.w, sb + 48)
    FMA16(xq1.x, sb + 64) FMA16(xq1.y, sb + 80) FMA16(xq1.z, sb + 96) FMA16(xq1.w, sb + 112)

    if (ck < 5) ISSUE(ck + 3)  // slot (ck+3)&3 = (ck-1)&3, freed by top barrier
  }

  __syncthreads();  // staging fully consumed; safe to alias xs as z-exchange

  // ---- combine k-quarter partials via LDS (aliased over xs) ----
  float* zx = &xs[0][0][0];  // [3][64][ZXST] = 15.4 KB < 32 KB
  if (w > 0) {
    float4* zp = (float4*)&zx[((w - 1) * 64 + lane) * ZXST];
    zp[0] = make_float4(z[0], z[1], z[2], z[3]);
    zp[1] = make_float4(z[4], z[5], z[6], z[7]);
    zp[2] = make_float4(z[8], z[9], z[10], z[11]);
    zp[3] = make_float4(z[12], z[13], z[14], z[15]);
  }
  __syncthreads();

  if (w == 0) {
#pragma unroll
    for (int p = 0; p < 3; ++p) {
      const float4* zp = (const float4*)&zx[(p * 64 + lane) * ZXST];
      const float4 a0 = zp[0], a1 = zp[1], a2 = zp[2], a3 = zp[3];
      z[0] += a0.x;  z[1] += a0.y;  z[2] += a0.z;  z[3] += a0.w;
      z[4] += a1.x;  z[5] += a1.y;  z[6] += a1.z;  z[7] += a1.w;
      z[8] += a2.x;  z[9] += a2.y;  z[10] += a2.z; z[11] += a2.w;
      z[12] += a3.x; z[13] += a3.y; z[14] += a3.z; z[15] += a3.w;
    }

    // ---------------- per-lane epilogue (row = rb + lane) ----------------
    float f[16];
#pragma unroll
    for (int c = 0; c < 16; ++c) f[c] = silu_g(z[c]);

    // T = f @ U2 (unnormalized; U2 orthogonal => scales cancel in P)
    const float* __restrict__ u2 = ws + U2_OFF;
    float T[16];
#pragma unroll
    for (int j = 0; j < 16; ++j) T[j] = 0.f;
#pragma unroll
    for (int c = 0; c < 16; ++c) {
      const float fc = f[c];
#pragma unroll
      for (int j = 0; j < 16; ++j) T[j] = fmaf(fc, u2[c * 16 + j], T[j]);
    }

    // e[t] = T[t]^2 + T[t+8]^2 ; P = e / sum(e)
    float e[8], es = 0.f;
#pragma unroll
    for (int tt = 0; tt < 8; ++tt) {
      e[tt] = fmaf(T[tt], T[tt], T[tt + 8] * T[tt + 8]);
      es += e[tt];
    }
    const float rinv = 1.f / fmaxf(es, 1e-35f);

    float P[8], lp[8];
#pragma unroll
    for (int tt = 0; tt < 8; ++tt) {
      P[tt] = e[tt] * rinv;
      lp[tt] = __logf(fmaxf(P[tt], 1e-12f));
    }

    const int row = rb + lane;
    float4* o0 = (float4*)(out + (size_t)row * 8);
    o0[0] = make_float4(lp[0], lp[1], lp[2], lp[3]);
    o0[1] = make_float4(lp[4], lp[5], lp[6], lp[7]);
    float4* o1 = (float4*)(out + (size_t)N_ROWS * 8 + (size_t)row * 8);
    o1[0] = make_float4(P[0], P[1], P[2], P[3]);
    o1[1] = make_float4(P[4], P[5], P[6], P[7]);
  }
#undef ISSUE
}

extern "C" void kernel_launch(void* const* d_in, const int* in_sizes, int n_in,
                              void* d_out, int out_size, void* d_ws, size_t ws_size,
                              hipStream_t stream) {
  const float* x = (const float*)d_in[0];
  const float* thc = (const float*)d_in[1];
  const float* th2 = (const float*)d_in[2];
  float* out = (float*)d_out;
  float* ws = (float*)d_ws;

  build_states_kernel<<<17, 64, 0, stream>>>(thc, th2, ws);
  hadamard_main_kernel<<<N_ROWS / 64, 256, 0, stream>>>(x, ws, out);
}